// Round 4
// baseline (205.723 us; speedup 1.0000x reference)
//
#include <hip/hip_runtime.h>
#include <hip/hip_bf16.h>

// MHA forward, all-bf16 MFMA pipeline (fp32 accum):
//  k1 convert: x,wq|wk|wv,wo fp32 -> bf16 (wqkv packed [3072][1024])
//  k2 gemm_qkv: xb @ wqkv^T (m97 2-barrier K-loop) -> qb (pre-scaled
//      log2e/8), kb, vtb[bh][64][2048]
//  k3 attn v4: Tq=128, 8 waves (qg, kh). K fragments global->reg,
//      PIPELINED ONE TILE AHEAD (v3 loaded and consumed K in the same
//      iter -> exposed L2 latency + the vmcnt wait drained the V
//      prefetch: 75us. v2 LDS-K was 49.6us). kfA/kfB named reg sets,
//      loop peeled even/odd (no runtime-indexed reg arrays). Barrier's
//      vmcnt(0) drain IS the wait point -- one full iter after issue.
//      Removes 40KB/iter of LDS traffic (K staging + K ds_reads) vs v2.
//      V stays LDS dbuf. LDS 36KB. launch_bounds(512,4).
//  k4 gemm_out: 128x64 tiles, grid 512 = 2 blocks/CU, swapped epilogue

typedef unsigned short u16;
typedef unsigned int u32;
using short8 = __attribute__((ext_vector_type(8))) short;
using f32x4  = __attribute__((ext_vector_type(4))) float;

#define WS_XB    0u
#define WS_WQKV  8388608u
#define WS_WOB   14680064u
#define WS_QB    16777216u
#define WS_KB    25165824u
#define WS_VTB   33554432u
#define WS_OB    41943040u

__device__ __forceinline__ u16 f2bf(float f) {
  u32 u = __float_as_uint(f);
  u += 0x7fffu + ((u >> 16) & 1u);
  return (u16)(u >> 16);
}

__device__ __forceinline__ ushort4 pk4(f32x4 v) {
  ushort4 r; r.x = f2bf(v[0]); r.y = f2bf(v[1]); r.z = f2bf(v[2]); r.w = f2bf(v[3]);
  return r;
}

__device__ __forceinline__ u32 pkbf2(float lo, float hi) {
  union { __hip_bfloat162 b; u32 u; } c;
  c.b = __float22bfloat162_rn(make_float2(lo, hi));
  return c.u;
}

__device__ __forceinline__ void gload16(const void* g, void* l) {
  __builtin_amdgcn_global_load_lds(
      (const __attribute__((address_space(1))) u32*)g,
      (__attribute__((address_space(3))) u32*)l, 16, 0, 0);
}

#define KSCALE 0.18033688011112042f  // log2(e)/sqrt(64)

// ---------------- k1: fp32 -> bf16 ----------------
__global__ void convert_k(const float* __restrict__ x, const float* __restrict__ wq,
                          const float* __restrict__ wk, const float* __restrict__ wv,
                          const float* __restrict__ wo,
                          u16* __restrict__ xb, u16* __restrict__ wqkv, u16* __restrict__ wob) {
  size_t g = ((size_t)blockIdx.x * 256 + threadIdx.x) * 4;
  const float* s; u16* d;
  if (g < 4194304u)      { s = x  + g;            d = xb   + g; }
  else if (g < 5242880u) { s = wq + (g - 4194304u); d = wqkv + (g - 4194304u); }
  else if (g < 6291456u) { s = wk + (g - 5242880u); d = wqkv + 1048576u + (g - 5242880u); }
  else if (g < 7340032u) { s = wv + (g - 6291456u); d = wqkv + 2097152u + (g - 6291456u); }
  else                   { s = wo + (g - 7340032u); d = wob  + (g - 7340032u); }
  float4 v = *(const float4*)s;
  f32x4 vv = {v.x, v.y, v.z, v.w};
  *(ushort4*)d = pk4(vv);
}

// ---------------- k2: QKV projection (single-buffer, m97 structure) ----------------
__global__ void gemm_qkv(const u16* __restrict__ A, const u16* __restrict__ Bt,
                         u16* __restrict__ qb, u16* __restrict__ kb, u16* __restrict__ vtb) {
  __shared__ __align__(16) u16 As[128 * 64];
  __shared__ __align__(16) u16 Bs[128 * 64];
  const int tid  = threadIdx.x;
  const int wave = tid >> 6, lane = tid & 63;
  const int c16  = lane & 15, quad = lane >> 4;
  const int tile_m = blockIdx.x * 128;
  const int tile_n = blockIdx.y * 128;
  const int wm = (wave >> 1) * 64, wn = (wave & 1) * 64;
  const int srow = wave * 32 + (lane >> 3);
  const int sc   = lane & 7;
  const int which = blockIdx.y >> 3;       // 0:Q 1:K 2:V
  const bool swp  = (which < 2);

  const u16* Pa = swp ? Bs : As;
  const u16* Pb = swp ? As : Bs;
  const int  ra = swp ? wn : wm;
  const int  rb = swp ? wm : wn;

  f32x4 acc[4][4] = {};

  for (int k0 = 0; k0 < 1024; k0 += 64) {
    __syncthreads();
#pragma unroll
    for (int j = 0; j < 4; ++j) {
      int row = srow + j * 8;
      int cp  = sc ^ (row & 7);
      gload16(A  + (size_t)(tile_m + row) * 1024 + k0 + cp * 8, As + row * 64 + sc * 8);
      gload16(Bt + (size_t)(tile_n + row) * 1024 + k0 + cp * 8, Bs + row * 64 + sc * 8);
    }
    __syncthreads();
#pragma unroll
    for (int kc = 0; kc < 2; ++kc) {
      const int ch = ((kc * 4 + quad) ^ (c16 & 7)) * 8;
      short8 fa[4], fb[4];
#pragma unroll
      for (int i = 0; i < 4; ++i)
        fa[i] = *(const short8*)(Pa + (ra + i * 16 + c16) * 64 + ch);
#pragma unroll
      for (int j = 0; j < 4; ++j)
        fb[j] = *(const short8*)(Pb + (rb + j * 16 + c16) * 64 + ch);
#pragma unroll
      for (int i = 0; i < 4; ++i)
#pragma unroll
        for (int j = 0; j < 4; ++j)
          acc[i][j] = __builtin_amdgcn_mfma_f32_16x16x32_bf16(fa[i], fb[j], acc[i][j], 0, 0, 0);
    }
  }

  if (which == 2) {
#pragma unroll
    for (int i = 0; i < 4; ++i) {
      int m0 = tile_m + wm + i * 16 + quad * 4;
      int bb = m0 >> 11, ss0 = m0 & 2047;
#pragma unroll
      for (int j = 0; j < 4; ++j) {
        int f = (tile_n & 1023) + wn + j * 16 + c16;
        int h = f >> 6, d = f & 63;
        *(ushort4*)(vtb + ((size_t)(bb * 16 + h) * 64 + d) * 2048 + ss0) = pk4(acc[i][j]);
      }
    }
  } else {
    u16* dstb = which ? kb : qb;
#pragma unroll
    for (int i = 0; i < 4; ++i) {
      int full = (tile_n & 1023) + wn + i * 16 + quad * 4;
      int h = full >> 6, d0 = full & 63;
#pragma unroll
      for (int j = 0; j < 4; ++j) {
        int t = tile_m + wm + j * 16 + c16;
        int bb = t >> 11, ss = t & 2047;
        f32x4 v = acc[i][j];
        if (which == 0) { v[0] *= KSCALE; v[1] *= KSCALE; v[2] *= KSCALE; v[3] *= KSCALE; }
        *(ushort4*)(dstb + ((size_t)(bb * 16 + h) * 2048 + ss) * 64 + d0) = pk4(v);
      }
    }
  }
}

// ---------------- k3: flash attention v4 -- K pipelined global->reg, V/P in LDS ----------------

// load K tile KT's fragments for this wave into reg set KF
#define LOAD_KF(KF, KT)                                                        \
  {                                                                            \
    _Pragma("unroll")                                                          \
    for (int kc = 0; kc < 2; ++kc)                                             \
      _Pragma("unroll")                                                        \
      for (int mi = 0; mi < 2; ++mi)                                           \
        KF[kc][mi] = *(const short8*)(kg +                                     \
            (size_t)((KT) * 64 + kh * 32 + mi * 16 + c16) * 64 +               \
            (kc * 4 + g4) * 8);                                                \
  }

// one K/V-tile step: QK^T (K from regs) -> fixed-max softmax -> P LDS -> PV
#define ATTN_STEP(KT, KF, VSB)                                                 \
  {                                                                            \
    f32x4 S[2][2] = {};                                                        \
    __builtin_amdgcn_s_setprio(1);                                             \
    _Pragma("unroll")                                                          \
    for (int kc = 0; kc < 2; ++kc)                                             \
      _Pragma("unroll")                                                        \
      for (int mi = 0; mi < 2; ++mi)                                           \
        _Pragma("unroll")                                                      \
        for (int nj = 0; nj < 2; ++nj)                                         \
          S[mi][nj] = __builtin_amdgcn_mfma_f32_16x16x32_bf16(                 \
              KF[kc][mi], qf[kc][nj], S[mi][nj], 0, 0, 0);                     \
    __builtin_amdgcn_s_setprio(0);                                             \
    uint2 mk[2];                                                               \
    _Pragma("unroll")                                                          \
    for (int mi = 0; mi < 2; ++mi)                                             \
      mk[mi] = *(const uint2*)(mask2 + (KT) * 32 + kh * 16 + mi * 8 + g4 * 2); \
    _Pragma("unroll")                                                          \
    for (int nj = 0; nj < 2; ++nj) {                                           \
      const int q = qg * 32 + nj * 16 + c16;                                   \
      _Pragma("unroll")                                                        \
      for (int mi = 0; mi < 2; ++mi) {                                         \
        float p0 = __builtin_amdgcn_exp2f(S[mi][nj][0]);                       \
        float p1 = __builtin_amdgcn_exp2f(S[mi][nj][1]);                       \
        float p2 = __builtin_amdgcn_exp2f(S[mi][nj][2]);                       \
        float p3 = __builtin_amdgcn_exp2f(S[mi][nj][3]);                       \
        u32 lo = pkbf2(p0, p1) & mk[mi].x;                                     \
        u32 hi = pkbf2(p2, p3) & mk[mi].y;                                     \
        uint2 pkd; pkd.x = lo; pkd.y = hi;                                     \
        const int c = kh * 4 + mi * 2 + (g4 >> 1);                             \
        *(uint2*)(Ps + q * 64 + ((c ^ (c16 & 7)) * 8 + (g4 & 1) * 4)) = pkd;   \
      }                                                                        \
    }                                                                          \
    {                                                                          \
      const int ch = ((kh * 4 + g4) ^ (c16 & 7)) * 8;                          \
      short8 a2[2], b2[4];                                                     \
      _Pragma("unroll")                                                        \
      for (int mi = 0; mi < 2; ++mi)                                           \
        a2[mi] = *(const short8*)(Ps + (qg * 32 + mi * 16 + c16) * 64 + ch);   \
      _Pragma("unroll")                                                        \
      for (int nd = 0; nd < 4; ++nd)                                           \
        b2[nd] = *(const short8*)((VSB) + (nd * 16 + c16) * 64 + ch);          \
      __builtin_amdgcn_s_setprio(1);                                           \
      _Pragma("unroll")                                                        \
      for (int mi = 0; mi < 2; ++mi) {                                         \
        _Pragma("unroll")                                                      \
        for (int nd = 0; nd < 4; ++nd)                                         \
          O[mi][nd] = __builtin_amdgcn_mfma_f32_16x16x32_bf16(                 \
              a2[mi], b2[nd], O[mi][nd], 0, 0, 0);                             \
        L[mi] = __builtin_amdgcn_mfma_f32_16x16x32_bf16(a2[mi], ones, L[mi],   \
                                                        0, 0, 0);              \
      }                                                                        \
      __builtin_amdgcn_s_setprio(0);                                           \
    }                                                                          \
  }

__global__ __launch_bounds__(512, 4) void attn_k(const u16* __restrict__ qb, const u16* __restrict__ kb,
                                                 const u16* __restrict__ vtb, const int* __restrict__ mask,
                                                 u16* __restrict__ ob) {
  // smem carve: Vs[2][4096]u16 @0 (16KB), Ps[128][64]u16 @16384 (16KB),
  // mask2[1024]u32 @32768 (4KB). Epilogue overlays [0,34304) as f32 reduce.
  __shared__ __align__(16) char smem[36864];
  u16* const VsB   = (u16*)smem;
  u16* const Ps    = (u16*)(smem + 16384);
  u32* const mask2 = (u32*)(smem + 32768);

  const int tid  = threadIdx.x;
  const int wave = tid >> 6, lane = tid & 63;
  const int c16  = lane & 15, g4 = lane >> 4;
  const int qg   = wave >> 1;        // q 32-block within tile (0..3)
  const int kh   = wave & 1;         // key half of the 64-key tile

  // XCD-bijective remap: flat = x + 16*y; xcd gets a contiguous 64-block chunk
  // = 4 bh x 16 q-blocks, so each bh's 512KB K/V is read within one L2.
  const int f    = blockIdx.x + 16 * blockIdx.y;
  const int i64  = f >> 3;
  const int bh   = (f & 7) * 4 + (i64 >> 4);
  const int q0   = (i64 & 15) * 128;
  const int bidx = bh >> 4, h = bh & 15;

  { // packed keep-masks for all 2048 keys (4 keys/thread)
    int4 m0 = *(const int4*)(mask + bidx * 2048 + tid * 4);
    uint2 dd;
    dd.x = (m0.x ? 0u : 0xFFFFu) | (m0.y ? 0u : 0xFFFF0000u);
    dd.y = (m0.z ? 0u : 0xFFFFu) | (m0.w ? 0u : 0xFFFF0000u);
    *(uint2*)(mask2 + tid * 2) = dd;
  }

  // Q fragments straight from global into registers
  const u16* qg_ = qb + ((size_t)bh * 2048 + q0 + qg * 32) * 64;
  short8 qf[2][2];
#pragma unroll
  for (int kc = 0; kc < 2; ++kc)
#pragma unroll
    for (int nj = 0; nj < 2; ++nj)
      qf[kc][nj] = *(const short8*)(qg_ + (nj * 16 + c16) * 64 + kc * 32 + g4 * 8);

  const u16* kg = kb  + (size_t)bh * 2048 * 64;
  const u16* vg = vtb + (size_t)bh * 64 * 2048;

  short8 kfA[2][2], kfB[2][2];   // K reg double-buffer (one tile ahead)

  { // stage V tile 0 into buffer 0; load K tile 0 into kfA
    int r  = tid >> 3;
    int cp = (tid & 7) ^ (r & 7);
    gload16(vg + (size_t)r * 2048 + cp * 8, VsB + tid * 8);
  }
  LOAD_KF(kfA, 0)
  __syncthreads();   // drains V(0) staging + kfA loads

  short8 ones;
#pragma unroll
  for (int i = 0; i < 8; ++i) ones[i] = (short)0x3F80;   // bf16 1.0

  f32x4 O[2][4] = {};   // partial over this wave's key half
  f32x4 L[2] = {};

  for (int kt2 = 0; kt2 < 16; ++kt2) {
    const int kt0 = kt2 * 2;
    // ---- even tile kt0: compute kfA/VsB[0]; prefetch K(kt0+1)->kfB, V(kt0+1)->VsB[1]
    if (kt2) __syncthreads();       // drains V(kt0)->buf0 + kfA(kt0) prefetch
    LOAD_KF(kfB, kt0 + 1)
    {
      int r  = tid >> 3;
      int cp = (tid & 7) ^ (r & 7);
      gload16(vg + (size_t)r * 2048 + (kt0 + 1) * 64 + cp * 8, VsB + 4096 + tid * 8);
    }
    ATTN_STEP(kt0, kfA, VsB)
    // ---- odd tile kt0+1: compute kfB/VsB[1]; prefetch K(kt0+2)->kfA, V(kt0+2)->VsB[0]
    __syncthreads();                // drains V(kt0+1)->buf1 + kfB prefetch
    if (kt2 < 15) {
      LOAD_KF(kfA, kt0 + 2)
      int r  = tid >> 3;
      int cp = (tid & 7) ^ (r & 7);
      gload16(vg + (size_t)r * 2048 + (kt0 + 2) * 64 + cp * 8, VsB + tid * 8);
    }
    ATTN_STEP(kt0 + 1, kfB, VsB + 4096)
  }

  // epilogue: merge the two key-half partials (fixed-max => pure addition),
  // then O/L. Reduce buffer overlays the dead V/P LDS (34304 <= 36864).
  __syncthreads();
  float* const redO = (float*)smem;            // [128][66] (+2 pad: 4-row bank spread)
  float* const redL = (float*)(smem + 33792);  // [128]
  if (kh) {
#pragma unroll
    for (int mi = 0; mi < 2; ++mi)
#pragma unroll
      for (int r = 0; r < 4; ++r) {
        int row = qg * 32 + mi * 16 + g4 * 4 + r;
#pragma unroll
        for (int nd = 0; nd < 4; ++nd)
          redO[row * 66 + nd * 16 + c16] = O[mi][nd][r];
        if (c16 == 0) redL[row] = L[mi][r];
      }
  }
  __syncthreads();
  if (!kh) {
    u16* og = ob + ((size_t)(bidx * 2048 + q0 + qg * 32)) * 1024 + h * 64;
#pragma unroll
    for (int mi = 0; mi < 2; ++mi)
#pragma unroll
      for (int r = 0; r < 4; ++r) {
        int row  = qg * 32 + mi * 16 + g4 * 4 + r;
        int qrow = mi * 16 + g4 * 4 + r;
        float linv = 1.f / (L[mi][r] + redL[row]);
#pragma unroll
        for (int nd = 0; nd < 4; ++nd) {
          float o = O[mi][nd][r] + redO[row * 66 + nd * 16 + c16];
          og[(size_t)qrow * 1024 + nd * 16 + c16] = f2bf(o * linv);
        }
      }
  }
}

// ---------------- k4: output projection, 128x64 tiles (2 blocks/CU) ----------------
__global__ __launch_bounds__(256) void gemm_out(const u16* __restrict__ A, const u16* __restrict__ Bt,
                         float* __restrict__ out) {
  __shared__ __align__(16) u16 As[128 * 64];
  __shared__ __align__(16) u16 Bs[64 * 64];
  const int tid  = threadIdx.x;
  const int wave = tid >> 6, lane = tid & 63;
  const int c16  = lane & 15, quad = lane >> 4;
  const int tile_m = blockIdx.x * 128;
  const int tile_n = blockIdx.y * 64;
  const int wm = wave * 32;
  const int sc   = lane & 7;

  f32x4 acc[4][2] = {};   // [feature blocks][token blocks]

  for (int k0 = 0; k0 < 1024; k0 += 64) {
    __syncthreads();
#pragma unroll
    for (int j = 0; j < 4; ++j) {      // A tile 128x64: 4 loads/thread
      int row = (tid >> 3) + j * 32;
      int cp  = sc ^ (row & 7);
      gload16(A + (size_t)(tile_m + row) * 1024 + k0 + cp * 8, As + row * 64 + sc * 8);
    }
#pragma unroll
    for (int j = 0; j < 2; ++j) {      // B tile 64x64: 2 loads/thread
      int row = (tid >> 3) + j * 32;
      int cp  = sc ^ (row & 7);
      gload16(Bt + (size_t)(tile_n + row) * 1024 + k0 + cp * 8, Bs + row * 64 + sc * 8);
    }
    __syncthreads();
#pragma unroll
    for (int kc = 0; kc < 2; ++kc) {
      const int ch = ((kc * 4 + quad) ^ (c16 & 7)) * 8;
      short8 fa[4], fb[2];
#pragma unroll
      for (int i = 0; i < 4; ++i)
        fa[i] = *(const short8*)(Bs + (i * 16 + c16) * 64 + ch);        // features
#pragma unroll
      for (int j = 0; j < 2; ++j)
        fb[j] = *(const short8*)(As + (wm + j * 16 + c16) * 64 + ch);   // tokens
#pragma unroll
      for (int i = 0; i < 4; ++i)
#pragma unroll
        for (int j = 0; j < 2; ++j)
          acc[i][j] = __builtin_amdgcn_mfma_f32_16x16x32_bf16(fa[i], fb[j], acc[i][j], 0, 0, 0);
    }
  }
#pragma unroll
  for (int i = 0; i < 4; ++i) {
    int f0 = tile_n + i * 16 + quad * 4;
#pragma unroll
    for (int j = 0; j < 2; ++j) {
      int t = tile_m + wm + j * 16 + c16;
      *(f32x4*)(out + (size_t)t * 1024 + f0) = acc[i][j];
    }
  }
}

extern "C" void kernel_launch(void* const* d_in, const int* in_sizes, int n_in,
                              void* d_out, int out_size, void* d_ws, size_t ws_size,
                              hipStream_t stream) {
  (void)in_sizes; (void)n_in; (void)out_size; (void)ws_size;
  const float* x    = (const float*)d_in[0];
  const int*   mask = (const int*)d_in[1];
  const float* wq   = (const float*)d_in[2];
  const float* wk   = (const float*)d_in[3];
  const float* wv   = (const float*)d_in[4];
  const float* wo   = (const float*)d_in[5];
  float* out = (float*)d_out;
  char*  ws  = (char*)d_ws;

  u16* xb   = (u16*)(ws + WS_XB);
  u16* wqkv = (u16*)(ws + WS_WQKV);
  u16* wob  = (u16*)(ws + WS_WOB);
  u16* qbuf = (u16*)(ws + WS_QB);
  u16* kbuf = (u16*)(ws + WS_KB);
  u16* vtb  = (u16*)(ws + WS_VTB);
  u16* obuf = (u16*)(ws + WS_OB);

  convert_k<<<8192, 256, 0, stream>>>(x, wq, wk, wv, wo, xb, wqkv, wob);
  gemm_qkv<<<dim3(32, 24), 256, 0, stream>>>(xb, wqkv, qbuf, kbuf, vtb);
  attn_k<<<dim3(16, 32), 512, 0, stream>>>(qbuf, kbuf, vtb, mask, obuf);
  gemm_out<<<dim3(32, 16), 256, 0, stream>>>(obuf, wob, out);
}

// Round 6
// 185.705 us; speedup vs baseline: 1.1078x; 1.1078x over previous
//
#include <hip/hip_runtime.h>
#include <hip/hip_bf16.h>

// MHA forward, all-bf16 MFMA pipeline (fp32 accum):
//  k1 convert: x,wq|wk|wv,wo fp32 -> bf16 (wqkv packed [3072][1024])
//  k2 gemm_qkv: xb @ wqkv^T (m97 2-barrier K-loop) -> qb (pre-scaled
//      log2e/8), kb, vtb[bh][64][2048]
//  k3 attn v5: v2 memory structure (K/V staged via gload_lds -- both
//      K-to-reg attempts failed: v3 exposed L2 latency 75us, v4 spilled
//      29MB scratch 85us) + SOFTMAX PIPELINE: at iter kt run PV(kt-1)
//      and QK(kt) as one MFMA cluster (P is wave-private: no barrier),
//      exp/pack(kt) trails as VALU overlapping other waves' MFMA.
//      P dbuf 2x16KB, V 3-buf 3x8KB (V(kt-1) outlives V(kt+1) stage),
//      K dbuf. LDS 76KB, 2 blocks/CU (grid-capped). 1 barrier/iter.
//  k4 gemm_out: 128x64 tiles, grid 512 = 2 blocks/CU, swapped epilogue

typedef unsigned short u16;
typedef unsigned int u32;
using short8 = __attribute__((ext_vector_type(8))) short;
using f32x4  = __attribute__((ext_vector_type(4))) float;

#define WS_XB    0u
#define WS_WQKV  8388608u
#define WS_WOB   14680064u
#define WS_QB    16777216u
#define WS_KB    25165824u
#define WS_VTB   33554432u
#define WS_OB    41943040u

__device__ __forceinline__ u16 f2bf(float f) {
  u32 u = __float_as_uint(f);
  u += 0x7fffu + ((u >> 16) & 1u);
  return (u16)(u >> 16);
}

__device__ __forceinline__ ushort4 pk4(f32x4 v) {
  ushort4 r; r.x = f2bf(v[0]); r.y = f2bf(v[1]); r.z = f2bf(v[2]); r.w = f2bf(v[3]);
  return r;
}

__device__ __forceinline__ u32 pkbf2(float lo, float hi) {
  union { __hip_bfloat162 b; u32 u; } c;
  c.b = __float22bfloat162_rn(make_float2(lo, hi));
  return c.u;
}

__device__ __forceinline__ void gload16(const void* g, void* l) {
  __builtin_amdgcn_global_load_lds(
      (const __attribute__((address_space(1))) u32*)g,
      (__attribute__((address_space(3))) u32*)l, 16, 0, 0);
}

#define KSCALE 0.18033688011112042f  // log2(e)/sqrt(64)

// ---------------- k1: fp32 -> bf16 ----------------
__global__ void convert_k(const float* __restrict__ x, const float* __restrict__ wq,
                          const float* __restrict__ wk, const float* __restrict__ wv,
                          const float* __restrict__ wo,
                          u16* __restrict__ xb, u16* __restrict__ wqkv, u16* __restrict__ wob) {
  size_t g = ((size_t)blockIdx.x * 256 + threadIdx.x) * 4;
  const float* s; u16* d;
  if (g < 4194304u)      { s = x  + g;            d = xb   + g; }
  else if (g < 5242880u) { s = wq + (g - 4194304u); d = wqkv + (g - 4194304u); }
  else if (g < 6291456u) { s = wk + (g - 5242880u); d = wqkv + 1048576u + (g - 5242880u); }
  else if (g < 7340032u) { s = wv + (g - 6291456u); d = wqkv + 2097152u + (g - 6291456u); }
  else                   { s = wo + (g - 7340032u); d = wob  + (g - 7340032u); }
  float4 v = *(const float4*)s;
  f32x4 vv = {v.x, v.y, v.z, v.w};
  *(ushort4*)d = pk4(vv);
}

// ---------------- k2: QKV projection (single-buffer, m97 structure) ----------------
__global__ void gemm_qkv(const u16* __restrict__ A, const u16* __restrict__ Bt,
                         u16* __restrict__ qb, u16* __restrict__ kb, u16* __restrict__ vtb) {
  __shared__ __align__(16) u16 As[128 * 64];
  __shared__ __align__(16) u16 Bs[128 * 64];
  const int tid  = threadIdx.x;
  const int wave = tid >> 6, lane = tid & 63;
  const int c16  = lane & 15, quad = lane >> 4;
  const int tile_m = blockIdx.x * 128;
  const int tile_n = blockIdx.y * 128;
  const int wm = (wave >> 1) * 64, wn = (wave & 1) * 64;
  const int srow = wave * 32 + (lane >> 3);
  const int sc   = lane & 7;
  const int which = blockIdx.y >> 3;       // 0:Q 1:K 2:V
  const bool swp  = (which < 2);

  const u16* Pa = swp ? Bs : As;
  const u16* Pb = swp ? As : Bs;
  const int  ra = swp ? wn : wm;
  const int  rb = swp ? wm : wn;

  f32x4 acc[4][4] = {};

  for (int k0 = 0; k0 < 1024; k0 += 64) {
    __syncthreads();
#pragma unroll
    for (int j = 0; j < 4; ++j) {
      int row = srow + j * 8;
      int cp  = sc ^ (row & 7);
      gload16(A  + (size_t)(tile_m + row) * 1024 + k0 + cp * 8, As + row * 64 + sc * 8);
      gload16(Bt + (size_t)(tile_n + row) * 1024 + k0 + cp * 8, Bs + row * 64 + sc * 8);
    }
    __syncthreads();
#pragma unroll
    for (int kc = 0; kc < 2; ++kc) {
      const int ch = ((kc * 4 + quad) ^ (c16 & 7)) * 8;
      short8 fa[4], fb[4];
#pragma unroll
      for (int i = 0; i < 4; ++i)
        fa[i] = *(const short8*)(Pa + (ra + i * 16 + c16) * 64 + ch);
#pragma unroll
      for (int j = 0; j < 4; ++j)
        fb[j] = *(const short8*)(Pb + (rb + j * 16 + c16) * 64 + ch);
#pragma unroll
      for (int i = 0; i < 4; ++i)
#pragma unroll
        for (int j = 0; j < 4; ++j)
          acc[i][j] = __builtin_amdgcn_mfma_f32_16x16x32_bf16(fa[i], fb[j], acc[i][j], 0, 0, 0);
    }
  }

  if (which == 2) {
#pragma unroll
    for (int i = 0; i < 4; ++i) {
      int m0 = tile_m + wm + i * 16 + quad * 4;
      int bb = m0 >> 11, ss0 = m0 & 2047;
#pragma unroll
      for (int j = 0; j < 4; ++j) {
        int f = (tile_n & 1023) + wn + j * 16 + c16;
        int h = f >> 6, d = f & 63;
        *(ushort4*)(vtb + ((size_t)(bb * 16 + h) * 64 + d) * 2048 + ss0) = pk4(acc[i][j]);
      }
    }
  } else {
    u16* dstb = which ? kb : qb;
#pragma unroll
    for (int i = 0; i < 4; ++i) {
      int full = (tile_n & 1023) + wn + i * 16 + quad * 4;
      int h = full >> 6, d0 = full & 63;
#pragma unroll
      for (int j = 0; j < 4; ++j) {
        int t = tile_m + wm + j * 16 + c16;
        int bb = t >> 11, ss = t & 2047;
        f32x4 v = acc[i][j];
        if (which == 0) { v[0] *= KSCALE; v[1] *= KSCALE; v[2] *= KSCALE; v[3] *= KSCALE; }
        *(ushort4*)(dstb + ((size_t)(bb * 16 + h) * 2048 + ss) * 64 + d0) = pk4(v);
      }
    }
  }
}

// ---------------- k3: flash attention v5 -- softmax-pipelined, all-LDS ----------------
__global__ __launch_bounds__(512) void attn_k(const u16* __restrict__ qb, const u16* __restrict__ kb,
                                              const u16* __restrict__ vtb, const int* __restrict__ mask,
                                              u16* __restrict__ ob) {
  // smem carve: Ks[2][4096]u16 @0 (16KB), Vs[3][4096]u16 @16384 (24KB),
  // Ps[2][8192]u16 @40960 (32KB), mask2[1024]u32 @73728 (4KB) = 76KB.
  // Epilogue overlays [0,34304) as f32 reduce buf.
  __shared__ __align__(16) char smem[77824];
  u16* const KsB   = (u16*)smem;
  u16* const VsB   = (u16*)(smem + 16384);
  u16* const PsB   = (u16*)(smem + 40960);
  u32* const mask2 = (u32*)(smem + 73728);

  const int tid  = threadIdx.x;
  const int wave = tid >> 6, lane = tid & 63;
  const int c16  = lane & 15, g4 = lane >> 4;
  const int qg   = wave >> 1;        // q 32-block within tile (0..3)
  const int kh   = wave & 1;         // key half of the 64-key tile

  // XCD-bijective remap: flat = x + 16*y; xcd gets a contiguous 64-block chunk
  // = 4 bh x 16 q-blocks, so each bh's 512KB K/V is read within one L2.
  const int f    = blockIdx.x + 16 * blockIdx.y;
  const int i64  = f >> 3;
  const int bh   = (f & 7) * 4 + (i64 >> 4);
  const int q0   = (i64 & 15) * 128;
  const int bidx = bh >> 4, h = bh & 15;

  { // packed keep-masks for all 2048 keys (4 keys/thread)
    int4 m0 = *(const int4*)(mask + bidx * 2048 + tid * 4);
    uint2 dd;
    dd.x = (m0.x ? 0u : 0xFFFFu) | (m0.y ? 0u : 0xFFFF0000u);
    dd.y = (m0.z ? 0u : 0xFFFFu) | (m0.w ? 0u : 0xFFFF0000u);
    *(uint2*)(mask2 + tid * 2) = dd;
  }

  // Q fragments straight from global into registers
  const u16* qg_ = qb + ((size_t)bh * 2048 + q0 + qg * 32) * 64;
  short8 qf[2][2];
#pragma unroll
  for (int kc = 0; kc < 2; ++kc)
#pragma unroll
    for (int nj = 0; nj < 2; ++nj)
      qf[kc][nj] = *(const short8*)(qg_ + (nj * 16 + c16) * 64 + kc * 32 + g4 * 8);

  const u16* kg = kb  + (size_t)bh * 2048 * 64;
  const u16* vg = vtb + (size_t)bh * 64 * 2048;
  { // stage K/V tile 0 into buffer 0
    int r  = tid >> 3;
    int cp = (tid & 7) ^ (r & 7);
    gload16(kg + (size_t)r * 64 + cp * 8,   KsB + tid * 8);
    gload16(vg + (size_t)r * 2048 + cp * 8, VsB + tid * 8);
  }
  __syncthreads();

  short8 ones;
#pragma unroll
  for (int i = 0; i < 8; ++i) ones[i] = (short)0x3F80;   // bf16 1.0

  f32x4 O[2][4] = {};   // partial over this wave's key half
  f32x4 L[2] = {};

  for (int kt = 0; kt < 32; ++kt) {
    if (kt) __syncthreads();   // drains tile-kt stages + frees overwritten bufs
    if (kt + 1 < 32) {         // prefetch tile kt+1
      int r  = tid >> 3;
      int cp = (tid & 7) ^ (r & 7);
      gload16(kg + (size_t)((kt + 1) * 64 + r) * 64 + cp * 8,
              KsB + ((kt + 1) & 1) * 4096 + tid * 8);
      gload16(vg + (size_t)r * 2048 + (kt + 1) * 64 + cp * 8,
              VsB + ((kt + 1) % 3) * 4096 + tid * 8);
    }

    // ---- LDS operand reads: PV(kt-1) operands + QK(kt) operands
    short8 a2[2], b2[4];       // PV: P(kt-1) rows, V(kt-1) rows
    if (kt) {
      const u16* psb = PsB + ((kt - 1) & 1) * 8192;
      const u16* vsb = VsB + ((kt - 1) % 3) * 4096;
      const int ch = ((kh * 4 + g4) ^ (c16 & 7)) * 8;
#pragma unroll
      for (int mi = 0; mi < 2; ++mi)
        a2[mi] = *(const short8*)(psb + (qg * 32 + mi * 16 + c16) * 64 + ch);
#pragma unroll
      for (int nd = 0; nd < 4; ++nd)
        b2[nd] = *(const short8*)(vsb + (nd * 16 + c16) * 64 + ch);
    }
    short8 ka[2][2];           // QK: K(kt) rows (this wave's kh half)
    {
      const u16* ksb = KsB + (kt & 1) * 4096;
#pragma unroll
      for (int kc = 0; kc < 2; ++kc) {
        const int ch = ((kc * 4 + g4) ^ (c16 & 7)) * 8;
#pragma unroll
        for (int mi = 0; mi < 2; ++mi)
          ka[kc][mi] = *(const short8*)(ksb + (kh * 32 + mi * 16 + c16) * 64 + ch);
      }
    }

    // ---- fused MFMA cluster: PV(kt-1) then QK(kt) (independent)
    f32x4 S[2][2] = {};
    __builtin_amdgcn_s_setprio(1);
    if (kt) {
#pragma unroll
      for (int mi = 0; mi < 2; ++mi) {
#pragma unroll
        for (int nd = 0; nd < 4; ++nd)
          O[mi][nd] = __builtin_amdgcn_mfma_f32_16x16x32_bf16(a2[mi], b2[nd], O[mi][nd], 0, 0, 0);
        L[mi] = __builtin_amdgcn_mfma_f32_16x16x32_bf16(a2[mi], ones, L[mi], 0, 0, 0);
      }
    }
#pragma unroll
    for (int kc = 0; kc < 2; ++kc)
#pragma unroll
      for (int mi = 0; mi < 2; ++mi)
#pragma unroll
        for (int nj = 0; nj < 2; ++nj)
          S[mi][nj] = __builtin_amdgcn_mfma_f32_16x16x32_bf16(ka[kc][mi], qf[kc][nj], S[mi][nj], 0, 0, 0);
    __builtin_amdgcn_s_setprio(0);

    // ---- trailing VALU: fixed-max softmax, P(kt) -> LDS (wave-private)
    uint2 mk[2];
#pragma unroll
    for (int mi = 0; mi < 2; ++mi)
      mk[mi] = *(const uint2*)(mask2 + kt * 32 + kh * 16 + mi * 8 + g4 * 2);
    u16* psw = PsB + (kt & 1) * 8192;
#pragma unroll
    for (int nj = 0; nj < 2; ++nj) {
      const int q = qg * 32 + nj * 16 + c16;
#pragma unroll
      for (int mi = 0; mi < 2; ++mi) {
        float p0 = __builtin_amdgcn_exp2f(S[mi][nj][0]);
        float p1 = __builtin_amdgcn_exp2f(S[mi][nj][1]);
        float p2 = __builtin_amdgcn_exp2f(S[mi][nj][2]);
        float p3 = __builtin_amdgcn_exp2f(S[mi][nj][3]);
        u32 lo = pkbf2(p0, p1) & mk[mi].x;
        u32 hi = pkbf2(p2, p3) & mk[mi].y;
        uint2 pkd; pkd.x = lo; pkd.y = hi;
        const int c = kh * 4 + mi * 2 + (g4 >> 1);
        *(uint2*)(psw + q * 64 + ((c ^ (c16 & 7)) * 8 + (g4 & 1) * 4)) = pkd;
      }
    }
  }

  { // ---- tail: PV(31) (P in Ps[1], V in Vs[31%3=1]; both wave-local-ready)
    const u16* psb = PsB + 8192;
    const u16* vsb = VsB + 4096;
    const int ch = ((kh * 4 + g4) ^ (c16 & 7)) * 8;
    short8 a2[2], b2[4];
#pragma unroll
    for (int mi = 0; mi < 2; ++mi)
      a2[mi] = *(const short8*)(psb + (qg * 32 + mi * 16 + c16) * 64 + ch);
#pragma unroll
    for (int nd = 0; nd < 4; ++nd)
      b2[nd] = *(const short8*)(vsb + (nd * 16 + c16) * 64 + ch);
#pragma unroll
    for (int mi = 0; mi < 2; ++mi) {
#pragma unroll
      for (int nd = 0; nd < 4; ++nd)
        O[mi][nd] = __builtin_amdgcn_mfma_f32_16x16x32_bf16(a2[mi], b2[nd], O[mi][nd], 0, 0, 0);
      L[mi] = __builtin_amdgcn_mfma_f32_16x16x32_bf16(a2[mi], ones, L[mi], 0, 0, 0);
    }
  }

  // epilogue: merge the two key-half partials (fixed-max => pure addition),
  // then O/L. Reduce buffer overlays the dead K/V/P LDS (34304 <= 77824).
  __syncthreads();
  float* const redO = (float*)smem;            // [128][66] (+2 pad: 4-row bank spread)
  float* const redL = (float*)(smem + 33792);  // [128]
  if (kh) {
#pragma unroll
    for (int mi = 0; mi < 2; ++mi)
#pragma unroll
      for (int r = 0; r < 4; ++r) {
        int row = qg * 32 + mi * 16 + g4 * 4 + r;
#pragma unroll
        for (int nd = 0; nd < 4; ++nd)
          redO[row * 66 + nd * 16 + c16] = O[mi][nd][r];
        if (c16 == 0) redL[row] = L[mi][r];
      }
  }
  __syncthreads();
  if (!kh) {
    u16* og = ob + ((size_t)(bidx * 2048 + q0 + qg * 32)) * 1024 + h * 64;
#pragma unroll
    for (int mi = 0; mi < 2; ++mi)
#pragma unroll
      for (int r = 0; r < 4; ++r) {
        int row  = qg * 32 + mi * 16 + g4 * 4 + r;
        int qrow = mi * 16 + g4 * 4 + r;
        float linv = 1.f / (L[mi][r] + redL[row]);
#pragma unroll
        for (int nd = 0; nd < 4; ++nd) {
          float o = O[mi][nd][r] + redO[row * 66 + nd * 16 + c16];
          og[(size_t)qrow * 1024 + nd * 16 + c16] = f2bf(o * linv);
        }
      }
  }
}

// ---------------- k4: output projection, 128x64 tiles (2 blocks/CU) ----------------
__global__ __launch_bounds__(256) void gemm_out(const u16* __restrict__ A, const u16* __restrict__ Bt,
                         float* __restrict__ out) {
  __shared__ __align__(16) u16 As[128 * 64];
  __shared__ __align__(16) u16 Bs[64 * 64];
  const int tid  = threadIdx.x;
  const int wave = tid >> 6, lane = tid & 63;
  const int c16  = lane & 15, quad = lane >> 4;
  const int tile_m = blockIdx.x * 128;
  const int tile_n = blockIdx.y * 64;
  const int wm = wave * 32;
  const int sc   = lane & 7;

  f32x4 acc[4][2] = {};   // [feature blocks][token blocks]

  for (int k0 = 0; k0 < 1024; k0 += 64) {
    __syncthreads();
#pragma unroll
    for (int j = 0; j < 4; ++j) {      // A tile 128x64: 4 loads/thread
      int row = (tid >> 3) + j * 32;
      int cp  = sc ^ (row & 7);
      gload16(A + (size_t)(tile_m + row) * 1024 + k0 + cp * 8, As + row * 64 + sc * 8);
    }
#pragma unroll
    for (int j = 0; j < 2; ++j) {      // B tile 64x64: 2 loads/thread
      int row = (tid >> 3) + j * 32;
      int cp  = sc ^ (row & 7);
      gload16(Bt + (size_t)(tile_n + row) * 1024 + k0 + cp * 8, Bs + row * 64 + sc * 8);
    }
    __syncthreads();
#pragma unroll
    for (int kc = 0; kc < 2; ++kc) {
      const int ch = ((kc * 4 + quad) ^ (c16 & 7)) * 8;
      short8 fa[4], fb[2];
#pragma unroll
      for (int i = 0; i < 4; ++i)
        fa[i] = *(const short8*)(Bs + (i * 16 + c16) * 64 + ch);        // features
#pragma unroll
      for (int j = 0; j < 2; ++j)
        fb[j] = *(const short8*)(As + (wm + j * 16 + c16) * 64 + ch);   // tokens
#pragma unroll
      for (int i = 0; i < 4; ++i)
#pragma unroll
        for (int j = 0; j < 2; ++j)
          acc[i][j] = __builtin_amdgcn_mfma_f32_16x16x32_bf16(fa[i], fb[j], acc[i][j], 0, 0, 0);
    }
  }
#pragma unroll
  for (int i = 0; i < 4; ++i) {
    int f0 = tile_n + i * 16 + quad * 4;
#pragma unroll
    for (int j = 0; j < 2; ++j) {
      int t = tile_m + wm + j * 16 + c16;
      *(f32x4*)(out + (size_t)t * 1024 + f0) = acc[i][j];
    }
  }
}

extern "C" void kernel_launch(void* const* d_in, const int* in_sizes, int n_in,
                              void* d_out, int out_size, void* d_ws, size_t ws_size,
                              hipStream_t stream) {
  (void)in_sizes; (void)n_in; (void)out_size; (void)ws_size;
  const float* x    = (const float*)d_in[0];
  const int*   mask = (const int*)d_in[1];
  const float* wq   = (const float*)d_in[2];
  const float* wk   = (const float*)d_in[3];
  const float* wv   = (const float*)d_in[4];
  const float* wo   = (const float*)d_in[5];
  float* out = (float*)d_out;
  char*  ws  = (char*)d_ws;

  u16* xb   = (u16*)(ws + WS_XB);
  u16* wqkv = (u16*)(ws + WS_WQKV);
  u16* wob  = (u16*)(ws + WS_WOB);
  u16* qbuf = (u16*)(ws + WS_QB);
  u16* kbuf = (u16*)(ws + WS_KB);
  u16* vtb  = (u16*)(ws + WS_VTB);
  u16* obuf = (u16*)(ws + WS_OB);

  convert_k<<<8192, 256, 0, stream>>>(x, wq, wk, wv, wo, xb, wqkv, wob);
  gemm_qkv<<<dim3(32, 24), 256, 0, stream>>>(xb, wqkv, qbuf, kbuf, vtb);
  attn_k<<<dim3(16, 32), 512, 0, stream>>>(qbuf, kbuf, vtb, mask, obuf);
  gemm_out<<<dim3(32, 16), 256, 0, stream>>>(obuf, wob, out);
}

// Round 7
// 184.067 us; speedup vs baseline: 1.1177x; 1.0089x over previous
//
#include <hip/hip_runtime.h>
#include <hip/hip_bf16.h>

// MHA forward, all-bf16 MFMA pipeline (fp32 accum):
//  k1 convert: x,wq|wk|wv,wo fp32 -> bf16 (wqkv packed [3072][1024])
//  k2 gemm_qkv: xb @ wqkv^T (m97 2-barrier K-loop) -> qb (pre-scaled
//      log2e/8), kb, vtb[bh][64][2048]
//  k3 attn v6: v2 staging (K/V dbuf gload_lds, 1 barrier/iter) but QK/PV
//      in 32x32x16 MFMA with IN-REGISTER P (T12): S^T lane = q-column,
//      16 key-rows in regs; exp2 + packed-bf16 mask-AND; 8 cvt_pk +
//      4 v_permlane32_swap_b32 build PV A-frags in-reg. P LDS round-trip
//      (8 writes + 2 reads/wave-iter) deleted -- v2's LDS pipe was ~85%
//      issue-busy, the proven limiter (v3/v4 K-to-reg and v5 softmax
//      pipeline all failed to beat 49.6). L summed in-lane from packed
//      masked P, merged via swap + small LDS in epilogue. LDS 36KB.
//  k4 gemm_out: 128x64 tiles, grid 512 = 2 blocks/CU, swapped epilogue

typedef unsigned short u16;
typedef unsigned int u32;
using short8 = __attribute__((ext_vector_type(8))) short;
using f32x4  = __attribute__((ext_vector_type(4))) float;
using f32x16 = __attribute__((ext_vector_type(16))) float;

#define WS_XB    0u
#define WS_WQKV  8388608u
#define WS_WOB   14680064u
#define WS_QB    16777216u
#define WS_KB    25165824u
#define WS_VTB   33554432u
#define WS_OB    41943040u

__device__ __forceinline__ u16 f2bf(float f) {
  u32 u = __float_as_uint(f);
  u += 0x7fffu + ((u >> 16) & 1u);
  return (u16)(u >> 16);
}

__device__ __forceinline__ ushort4 pk4(f32x4 v) {
  ushort4 r; r.x = f2bf(v[0]); r.y = f2bf(v[1]); r.z = f2bf(v[2]); r.w = f2bf(v[3]);
  return r;
}

__device__ __forceinline__ u32 pkbf2(float lo, float hi) {
  union { __hip_bfloat162 b; u32 u; } c;
  c.b = __float22bfloat162_rn(make_float2(lo, hi));
  return c.u;
}

__device__ __forceinline__ void gload16(const void* g, void* l) {
  __builtin_amdgcn_global_load_lds(
      (const __attribute__((address_space(1))) u32*)g,
      (__attribute__((address_space(3))) u32*)l, 16, 0, 0);
}

#define KSCALE 0.18033688011112042f  // log2(e)/sqrt(64)

// ---------------- k1: fp32 -> bf16 ----------------
__global__ void convert_k(const float* __restrict__ x, const float* __restrict__ wq,
                          const float* __restrict__ wk, const float* __restrict__ wv,
                          const float* __restrict__ wo,
                          u16* __restrict__ xb, u16* __restrict__ wqkv, u16* __restrict__ wob) {
  size_t g = ((size_t)blockIdx.x * 256 + threadIdx.x) * 4;
  const float* s; u16* d;
  if (g < 4194304u)      { s = x  + g;            d = xb   + g; }
  else if (g < 5242880u) { s = wq + (g - 4194304u); d = wqkv + (g - 4194304u); }
  else if (g < 6291456u) { s = wk + (g - 5242880u); d = wqkv + 1048576u + (g - 5242880u); }
  else if (g < 7340032u) { s = wv + (g - 6291456u); d = wqkv + 2097152u + (g - 6291456u); }
  else                   { s = wo + (g - 7340032u); d = wob  + (g - 7340032u); }
  float4 v = *(const float4*)s;
  f32x4 vv = {v.x, v.y, v.z, v.w};
  *(ushort4*)d = pk4(vv);
}

// ---------------- k2: QKV projection (single-buffer, m97 structure) ----------------
__global__ void gemm_qkv(const u16* __restrict__ A, const u16* __restrict__ Bt,
                         u16* __restrict__ qb, u16* __restrict__ kb, u16* __restrict__ vtb) {
  __shared__ __align__(16) u16 As[128 * 64];
  __shared__ __align__(16) u16 Bs[128 * 64];
  const int tid  = threadIdx.x;
  const int wave = tid >> 6, lane = tid & 63;
  const int c16  = lane & 15, quad = lane >> 4;
  const int tile_m = blockIdx.x * 128;
  const int tile_n = blockIdx.y * 128;
  const int wm = (wave >> 1) * 64, wn = (wave & 1) * 64;
  const int srow = wave * 32 + (lane >> 3);
  const int sc   = lane & 7;
  const int which = blockIdx.y >> 3;       // 0:Q 1:K 2:V
  const bool swp  = (which < 2);

  const u16* Pa = swp ? Bs : As;
  const u16* Pb = swp ? As : Bs;
  const int  ra = swp ? wn : wm;
  const int  rb = swp ? wm : wn;

  f32x4 acc[4][4] = {};

  for (int k0 = 0; k0 < 1024; k0 += 64) {
    __syncthreads();
#pragma unroll
    for (int j = 0; j < 4; ++j) {
      int row = srow + j * 8;
      int cp  = sc ^ (row & 7);
      gload16(A  + (size_t)(tile_m + row) * 1024 + k0 + cp * 8, As + row * 64 + sc * 8);
      gload16(Bt + (size_t)(tile_n + row) * 1024 + k0 + cp * 8, Bs + row * 64 + sc * 8);
    }
    __syncthreads();
#pragma unroll
    for (int kc = 0; kc < 2; ++kc) {
      const int ch = ((kc * 4 + quad) ^ (c16 & 7)) * 8;
      short8 fa[4], fb[4];
#pragma unroll
      for (int i = 0; i < 4; ++i)
        fa[i] = *(const short8*)(Pa + (ra + i * 16 + c16) * 64 + ch);
#pragma unroll
      for (int j = 0; j < 4; ++j)
        fb[j] = *(const short8*)(Pb + (rb + j * 16 + c16) * 64 + ch);
#pragma unroll
      for (int i = 0; i < 4; ++i)
#pragma unroll
        for (int j = 0; j < 4; ++j)
          acc[i][j] = __builtin_amdgcn_mfma_f32_16x16x32_bf16(fa[i], fb[j], acc[i][j], 0, 0, 0);
    }
  }

  if (which == 2) {
#pragma unroll
    for (int i = 0; i < 4; ++i) {
      int m0 = tile_m + wm + i * 16 + quad * 4;
      int bb = m0 >> 11, ss0 = m0 & 2047;
#pragma unroll
      for (int j = 0; j < 4; ++j) {
        int f = (tile_n & 1023) + wn + j * 16 + c16;
        int h = f >> 6, d = f & 63;
        *(ushort4*)(vtb + ((size_t)(bb * 16 + h) * 64 + d) * 2048 + ss0) = pk4(acc[i][j]);
      }
    }
  } else {
    u16* dstb = which ? kb : qb;
#pragma unroll
    for (int i = 0; i < 4; ++i) {
      int full = (tile_n & 1023) + wn + i * 16 + quad * 4;
      int h = full >> 6, d0 = full & 63;
#pragma unroll
      for (int j = 0; j < 4; ++j) {
        int t = tile_m + wm + j * 16 + c16;
        int bb = t >> 11, ss = t & 2047;
        f32x4 v = acc[i][j];
        if (which == 0) { v[0] *= KSCALE; v[1] *= KSCALE; v[2] *= KSCALE; v[3] *= KSCALE; }
        *(ushort4*)(dstb + ((size_t)(bb * 16 + h) * 2048 + ss) * 64 + d0) = pk4(v);
      }
    }
  }
}

// ---------------- k3: flash attention v6 -- 32x32 MFMA, in-register P ----------------
__global__ __launch_bounds__(512) void attn_k(const u16* __restrict__ qb, const u16* __restrict__ kb,
                                              const u16* __restrict__ vtb, const int* __restrict__ mask,
                                              u16* __restrict__ ob) {
  // smem: Ks[2][4096]u16 @0 (16KB), Vs[2][4096]u16 @16384 (16KB),
  // mask2[1024]u32 @32768 (4KB) = 36KB. Epilogue overlays [0,34816) as
  // redO[128][66] f32 @0, redL0[128] @33792, redL1[128] @34304.
  __shared__ __align__(16) char smem[36864];
  u16* const KsB   = (u16*)smem;
  u16* const VsB   = (u16*)(smem + 16384);
  u32* const mask2 = (u32*)(smem + 32768);

  const int tid  = threadIdx.x;
  const int wave = tid >> 6, lane = tid & 63;
  const int q32  = lane & 31, hi = lane >> 5;
  const int qg   = wave >> 1;        // q 32-block within tile (0..3)
  const int kh   = wave & 1;         // key half of the 64-key tile

  // XCD-bijective remap: flat = x + 16*y; xcd gets a contiguous 64-block chunk
  // = 4 bh x 16 q-blocks, so each bh's 512KB K/V is read within one L2.
  const int f    = blockIdx.x + 16 * blockIdx.y;
  const int i64  = f >> 3;
  const int bh   = (f & 7) * 4 + (i64 >> 4);
  const int q0   = (i64 & 15) * 128;
  const int bidx = bh >> 4, h = bh & 15;

  { // packed keep-masks for all 2048 keys (4 keys/thread)
    int4 m0 = *(const int4*)(mask + bidx * 2048 + tid * 4);
    uint2 dd;
    dd.x = (m0.x ? 0u : 0xFFFFu) | (m0.y ? 0u : 0xFFFF0000u);
    dd.y = (m0.z ? 0u : 0xFFFFu) | (m0.w ? 0u : 0xFFFF0000u);
    *(uint2*)(mask2 + tid * 2) = dd;
  }

  // Q fragments (B-operand of 32x32x16: col=q=lane&31, k=d=(lane>>5)*8+j)
  const u16* qg_ = qb + ((size_t)bh * 2048 + q0 + qg * 32) * 64;
  short8 qf[4];
#pragma unroll
  for (int kc = 0; kc < 4; ++kc)
    qf[kc] = *(const short8*)(qg_ + q32 * 64 + kc * 16 + hi * 8);

  const u16* kg = kb  + (size_t)bh * 2048 * 64;
  const u16* vg = vtb + (size_t)bh * 64 * 2048;
  { // stage K/V tile 0 into buffer 0
    int r  = tid >> 3;
    int cp = (tid & 7) ^ (r & 7);
    gload16(kg + (size_t)r * 64 + cp * 8,   KsB + tid * 8);
    gload16(vg + (size_t)r * 2048 + cp * 8, VsB + tid * 8);
  }
  __syncthreads();

  f32x16 O[2] = {};   // O[nb]: rows q=(r&3)+8*(r>>2)+4*hi, col d=nb*32+q32
  float  Lv   = 0.f;  // running sum of this lane's 16 masked P values (q=q32)

  const int krow = kh * 32 + q32;    // K row this lane provides (A-operand)

  for (int kt = 0; kt < 32; ++kt) {
    if (kt) __syncthreads();   // drains tile-kt stages + frees other buffer
    if (kt + 1 < 32) {
      const int nb = (kt + 1) & 1;
      int r  = tid >> 3;
      int cp = (tid & 7) ^ (r & 7);
      gload16(kg + (size_t)((kt + 1) * 64 + r) * 64 + cp * 8, KsB + nb * 4096 + tid * 8);
      gload16(vg + (size_t)r * 2048 + (kt + 1) * 64 + cp * 8, VsB + nb * 4096 + tid * 8);
    }
    const u16* ksb = KsB + (kt & 1) * 4096;
    const u16* vsb = VsB + (kt & 1) * 4096;

    // K frags: A-operand (row=key=krow, k=d-slice); 4x ds_read_b128
    short8 ka[4];
#pragma unroll
    for (int kc = 0; kc < 4; ++kc) {
      const int c8 = (kc * 2 + hi) ^ (krow & 7);
      ka[kc] = *(const short8*)(ksb + krow * 64 + c8 * 8);
    }

    // S^T[key 32][q 32] in one 32x32 acc; lane: col q=q32, rows crow(r,hi)
    f32x16 S = {};
    __builtin_amdgcn_s_setprio(1);
#pragma unroll
    for (int kc = 0; kc < 4; ++kc)
      S = __builtin_amdgcn_mfma_f32_32x32x16_bf16(ka[kc], qf[kc], S, 0, 0, 0);
    __builtin_amdgcn_s_setprio(0);

    // fixed-max softmax in-register: p[r]=exp2(S[r]) for key=(r&3)+8(r>>2)+4hi;
    // pack bf16 pairs, AND keep-mask, accumulate L from packed (masked) values.
    u32 X[4][2];
#pragma unroll
    for (int g = 0; g < 4; ++g) {
      uint2 mg = *(const uint2*)(mask2 + kt * 32 + kh * 16 + g * 4 + hi * 2);
      float p0 = __builtin_amdgcn_exp2f(S[4 * g + 0]);
      float p1 = __builtin_amdgcn_exp2f(S[4 * g + 1]);
      float p2 = __builtin_amdgcn_exp2f(S[4 * g + 2]);
      float p3 = __builtin_amdgcn_exp2f(S[4 * g + 3]);
      u32 x0 = pkbf2(p0, p1) & mg.x;
      u32 x1 = pkbf2(p2, p3) & mg.y;
      Lv += __uint_as_float(x0 << 16) + __uint_as_float(x0 & 0xFFFF0000u)
          + __uint_as_float(x1 << 16) + __uint_as_float(x1 & 0xFFFF0000u);
      X[g][0] = x0; X[g][1] = x1;
    }

    // assemble PV A-frags in-register: pa[kc] covers keys kc*16 + (hi*8..+7).
    // swap(a,b): a' = [a.lo, b.lo], b' = [a.hi, b.hi] -> words w0/w2 for
    // BOTH lane halves at once (w1/w3 from the e=1 packs).
    short8 pa0, pa1;
    {
      u32 a0 = X[0][0], b0 = X[1][0];
      asm("v_permlane32_swap_b32 %0, %1" : "+v"(a0), "+v"(b0));
      u32 a1 = X[0][1], b1 = X[1][1];
      asm("v_permlane32_swap_b32 %0, %1" : "+v"(a1), "+v"(b1));
      union { u32 u[4]; short8 s; } pw;
      pw.u[0] = a0; pw.u[1] = a1; pw.u[2] = b0; pw.u[3] = b1;
      pa0 = pw.s;
      u32 c0 = X[2][0], d0 = X[3][0];
      asm("v_permlane32_swap_b32 %0, %1" : "+v"(c0), "+v"(d0));
      u32 c1 = X[2][1], d1 = X[3][1];
      asm("v_permlane32_swap_b32 %0, %1" : "+v"(c1), "+v"(d1));
      union { u32 u[4]; short8 s; } pw2;
      pw2.u[0] = c0; pw2.u[1] = c1; pw2.u[2] = d0; pw2.u[3] = d1;
      pa1 = pw2.s;
    }

    // V frags: B-operand (col=d=nb*32+q32, k=key); 4x ds_read_b128; PV.
    short8 vb00, vb01, vb10, vb11;
    {
      const int r0 = q32, r1 = 32 + q32;
      vb00 = *(const short8*)(vsb + r0 * 64 + (((kh * 4 + 0 * 2 + hi) ^ (r0 & 7)) * 8));
      vb01 = *(const short8*)(vsb + r0 * 64 + (((kh * 4 + 1 * 2 + hi) ^ (r0 & 7)) * 8));
      vb10 = *(const short8*)(vsb + r1 * 64 + (((kh * 4 + 0 * 2 + hi) ^ (r1 & 7)) * 8));
      vb11 = *(const short8*)(vsb + r1 * 64 + (((kh * 4 + 1 * 2 + hi) ^ (r1 & 7)) * 8));
    }
    __builtin_amdgcn_s_setprio(1);
    O[0] = __builtin_amdgcn_mfma_f32_32x32x16_bf16(pa0, vb00, O[0], 0, 0, 0);
    O[0] = __builtin_amdgcn_mfma_f32_32x32x16_bf16(pa1, vb01, O[0], 0, 0, 0);
    O[1] = __builtin_amdgcn_mfma_f32_32x32x16_bf16(pa0, vb10, O[1], 0, 0, 0);
    O[1] = __builtin_amdgcn_mfma_f32_32x32x16_bf16(pa1, vb11, O[1], 0, 0, 0);
    __builtin_amdgcn_s_setprio(0);
  }

  // combine Lv across lane halves (lane l and l^32 share q): one swap + add
  float Lw;
  {
    u32 la = __float_as_uint(Lv), lb = la;
    asm("v_permlane32_swap_b32 %0, %1" : "+v"(la), "+v"(lb));
    Lw = __uint_as_float(la) + __uint_as_float(lb);
  }

  // epilogue: merge the two key-half partials (fixed-max => pure addition).
  __syncthreads();
  float* const redO  = (float*)smem;            // [128][66] (+2 pad)
  float* const redL0 = (float*)(smem + 33792);  // [128] kh=0 L
  float* const redL1 = (float*)(smem + 34304);  // [128] kh=1 L
  if (kh) {
#pragma unroll
    for (int qd = 0; qd < 4; ++qd)
#pragma unroll
      for (int t = 0; t < 4; ++t) {
        const int r   = qd * 4 + t;
        const int row = qg * 32 + qd * 8 + hi * 4 + t;
        redO[row * 66 +      q32] = O[0][r];
        redO[row * 66 + 32 + q32] = O[1][r];
      }
    if (lane < 32) redL1[qg * 32 + q32] = Lw;
  } else {
    if (lane < 32) redL0[qg * 32 + q32] = Lw;
  }
  __syncthreads();
  if (!kh) {
    u16* og = ob + ((size_t)(bidx * 2048 + q0 + qg * 32)) * 1024 + h * 64;
#pragma unroll
    for (int qd = 0; qd < 4; ++qd) {
      f32x4 l0 = *(const f32x4*)(redL0 + qg * 32 + qd * 8 + hi * 4);
      f32x4 l1 = *(const f32x4*)(redL1 + qg * 32 + qd * 8 + hi * 4);
#pragma unroll
      for (int t = 0; t < 4; ++t) {
        const int r    = qd * 4 + t;
        const int crow = qd * 8 + hi * 4 + t;
        const int row  = qg * 32 + crow;
        const float linv = 1.f / (l0[t] + l1[t]);
        og[(size_t)crow * 1024 +      q32] = f2bf((O[0][r] + redO[row * 66 +      q32]) * linv);
        og[(size_t)crow * 1024 + 32 + q32] = f2bf((O[1][r] + redO[row * 66 + 32 + q32]) * linv);
      }
    }
  }
}

// ---------------- k4: output projection, 128x64 tiles (2 blocks/CU) ----------------
__global__ __launch_bounds__(256) void gemm_out(const u16* __restrict__ A, const u16* __restrict__ Bt,
                         float* __restrict__ out) {
  __shared__ __align__(16) u16 As[128 * 64];
  __shared__ __align__(16) u16 Bs[64 * 64];
  const int tid  = threadIdx.x;
  const int wave = tid >> 6, lane = tid & 63;
  const int c16  = lane & 15, quad = lane >> 4;
  const int tile_m = blockIdx.x * 128;
  const int tile_n = blockIdx.y * 64;
  const int wm = wave * 32;
  const int sc   = lane & 7;

  f32x4 acc[4][2] = {};   // [feature blocks][token blocks]

  for (int k0 = 0; k0 < 1024; k0 += 64) {
    __syncthreads();
#pragma unroll
    for (int j = 0; j < 4; ++j) {      // A tile 128x64: 4 loads/thread
      int row = (tid >> 3) + j * 32;
      int cp  = sc ^ (row & 7);
      gload16(A + (size_t)(tile_m + row) * 1024 + k0 + cp * 8, As + row * 64 + sc * 8);
    }
#pragma unroll
    for (int j = 0; j < 2; ++j) {      // B tile 64x64: 2 loads/thread
      int row = (tid >> 3) + j * 32;
      int cp  = sc ^ (row & 7);
      gload16(Bt + (size_t)(tile_n + row) * 1024 + k0 + cp * 8, Bs + row * 64 + sc * 8);
    }
    __syncthreads();
#pragma unroll
    for (int kc = 0; kc < 2; ++kc) {
      const int ch = ((kc * 4 + quad) ^ (c16 & 7)) * 8;
      short8 fa[4], fb[2];
#pragma unroll
      for (int i = 0; i < 4; ++i)
        fa[i] = *(const short8*)(Bs + (i * 16 + c16) * 64 + ch);        // features
#pragma unroll
      for (int j = 0; j < 2; ++j)
        fb[j] = *(const short8*)(As + (wm + j * 16 + c16) * 64 + ch);   // tokens
#pragma unroll
      for (int i = 0; i < 4; ++i)
#pragma unroll
        for (int j = 0; j < 2; ++j)
          acc[i][j] = __builtin_amdgcn_mfma_f32_16x16x32_bf16(fa[i], fb[j], acc[i][j], 0, 0, 0);
    }
  }
#pragma unroll
  for (int i = 0; i < 4; ++i) {
    int f0 = tile_n + i * 16 + quad * 4;
#pragma unroll
    for (int j = 0; j < 2; ++j) {
      int t = tile_m + wm + j * 16 + c16;
      *(f32x4*)(out + (size_t)t * 1024 + f0) = acc[i][j];
    }
  }
}

extern "C" void kernel_launch(void* const* d_in, const int* in_sizes, int n_in,
                              void* d_out, int out_size, void* d_ws, size_t ws_size,
                              hipStream_t stream) {
  (void)in_sizes; (void)n_in; (void)out_size; (void)ws_size;
  const float* x    = (const float*)d_in[0];
  const int*   mask = (const int*)d_in[1];
  const float* wq   = (const float*)d_in[2];
  const float* wk   = (const float*)d_in[3];
  const float* wv   = (const float*)d_in[4];
  const float* wo   = (const float*)d_in[5];
  float* out = (float*)d_out;
  char*  ws  = (char*)d_ws;

  u16* xb   = (u16*)(ws + WS_XB);
  u16* wqkv = (u16*)(ws + WS_WQKV);
  u16* wob  = (u16*)(ws + WS_WOB);
  u16* qbuf = (u16*)(ws + WS_QB);
  u16* kbuf = (u16*)(ws + WS_KB);
  u16* vtb  = (u16*)(ws + WS_VTB);
  u16* obuf = (u16*)(ws + WS_OB);

  convert_k<<<8192, 256, 0, stream>>>(x, wq, wk, wv, wo, xb, wqkv, wob);
  gemm_qkv<<<dim3(32, 24), 256, 0, stream>>>(xb, wqkv, qbuf, kbuf, vtb);
  attn_k<<<dim3(16, 32), 512, 0, stream>>>(qbuf, kbuf, vtb, mask, obuf);
  gemm_out<<<dim3(32, 16), 256, 0, stream>>>(obuf, wob, out);
}

// Round 8
// 177.674 us; speedup vs baseline: 1.1579x; 1.0360x over previous
//
#include <hip/hip_runtime.h>
#include <hip/hip_bf16.h>

// MHA forward, all-bf16 MFMA pipeline (fp32 accum):
//  k1 convert: x,wq|wk|wv,wo fp32 -> bf16 (wqkv packed [3072][1024])
//  k2 gemm_qkv: xb @ wqkv^T (m97 2-barrier K-loop) -> qb (pre-scaled
//      log2e/8), kb, vtb[bh][64][2048]
//  k3 attn v2 (PROVEN BEST 49.6us -- restored): Tq=128, 8 waves (qg,kh),
//      K/V dbuf gload_lds, P via LDS, fixed-max softmax, 1 barrier/iter.
//      Falsified alternatives: v3 K-to-reg same-iter (75us, exposed L2
//      latency); v4 K-reg pipelined (85us, 29MB scratch spills at VGPR64);
//      v5 PV/QK softmax pipeline (53us, buffer rotation overhead);
//      v6 32x32 MFMA in-register P (54.6us, 32-row frag reads = 4-way
//      bank conflict 2.4M->4.2M + L-unpack VALU 40->51%).
//      16x16 frags read 16 rows/instr = 2-way conflict = free (m136).
//  k4 gemm_out: 128x64 tiles, grid 512 = 2 blocks/CU, swapped epilogue

typedef unsigned short u16;
typedef unsigned int u32;
using short8 = __attribute__((ext_vector_type(8))) short;
using f32x4  = __attribute__((ext_vector_type(4))) float;

#define WS_XB    0u
#define WS_WQKV  8388608u
#define WS_WOB   14680064u
#define WS_QB    16777216u
#define WS_KB    25165824u
#define WS_VTB   33554432u
#define WS_OB    41943040u

__device__ __forceinline__ u16 f2bf(float f) {
  u32 u = __float_as_uint(f);
  u += 0x7fffu + ((u >> 16) & 1u);
  return (u16)(u >> 16);
}

__device__ __forceinline__ ushort4 pk4(f32x4 v) {
  ushort4 r; r.x = f2bf(v[0]); r.y = f2bf(v[1]); r.z = f2bf(v[2]); r.w = f2bf(v[3]);
  return r;
}

__device__ __forceinline__ u32 pkbf2(float lo, float hi) {
  union { __hip_bfloat162 b; u32 u; } c;
  c.b = __float22bfloat162_rn(make_float2(lo, hi));
  return c.u;
}

__device__ __forceinline__ void gload16(const void* g, void* l) {
  __builtin_amdgcn_global_load_lds(
      (const __attribute__((address_space(1))) u32*)g,
      (__attribute__((address_space(3))) u32*)l, 16, 0, 0);
}

#define KSCALE 0.18033688011112042f  // log2(e)/sqrt(64)

// ---------------- k1: fp32 -> bf16 ----------------
__global__ void convert_k(const float* __restrict__ x, const float* __restrict__ wq,
                          const float* __restrict__ wk, const float* __restrict__ wv,
                          const float* __restrict__ wo,
                          u16* __restrict__ xb, u16* __restrict__ wqkv, u16* __restrict__ wob) {
  size_t g = ((size_t)blockIdx.x * 256 + threadIdx.x) * 4;
  const float* s; u16* d;
  if (g < 4194304u)      { s = x  + g;            d = xb   + g; }
  else if (g < 5242880u) { s = wq + (g - 4194304u); d = wqkv + (g - 4194304u); }
  else if (g < 6291456u) { s = wk + (g - 5242880u); d = wqkv + 1048576u + (g - 5242880u); }
  else if (g < 7340032u) { s = wv + (g - 6291456u); d = wqkv + 2097152u + (g - 6291456u); }
  else                   { s = wo + (g - 7340032u); d = wob  + (g - 7340032u); }
  float4 v = *(const float4*)s;
  f32x4 vv = {v.x, v.y, v.z, v.w};
  *(ushort4*)d = pk4(vv);
}

// ---------------- k2: QKV projection (single-buffer, m97 structure) ----------------
__global__ void gemm_qkv(const u16* __restrict__ A, const u16* __restrict__ Bt,
                         u16* __restrict__ qb, u16* __restrict__ kb, u16* __restrict__ vtb) {
  __shared__ __align__(16) u16 As[128 * 64];
  __shared__ __align__(16) u16 Bs[128 * 64];
  const int tid  = threadIdx.x;
  const int wave = tid >> 6, lane = tid & 63;
  const int c16  = lane & 15, quad = lane >> 4;
  const int tile_m = blockIdx.x * 128;
  const int tile_n = blockIdx.y * 128;
  const int wm = (wave >> 1) * 64, wn = (wave & 1) * 64;
  const int srow = wave * 32 + (lane >> 3);
  const int sc   = lane & 7;
  const int which = blockIdx.y >> 3;       // 0:Q 1:K 2:V
  const bool swp  = (which < 2);

  const u16* Pa = swp ? Bs : As;
  const u16* Pb = swp ? As : Bs;
  const int  ra = swp ? wn : wm;
  const int  rb = swp ? wm : wn;

  f32x4 acc[4][4] = {};

  for (int k0 = 0; k0 < 1024; k0 += 64) {
    __syncthreads();
#pragma unroll
    for (int j = 0; j < 4; ++j) {
      int row = srow + j * 8;
      int cp  = sc ^ (row & 7);
      gload16(A  + (size_t)(tile_m + row) * 1024 + k0 + cp * 8, As + row * 64 + sc * 8);
      gload16(Bt + (size_t)(tile_n + row) * 1024 + k0 + cp * 8, Bs + row * 64 + sc * 8);
    }
    __syncthreads();
#pragma unroll
    for (int kc = 0; kc < 2; ++kc) {
      const int ch = ((kc * 4 + quad) ^ (c16 & 7)) * 8;
      short8 fa[4], fb[4];
#pragma unroll
      for (int i = 0; i < 4; ++i)
        fa[i] = *(const short8*)(Pa + (ra + i * 16 + c16) * 64 + ch);
#pragma unroll
      for (int j = 0; j < 4; ++j)
        fb[j] = *(const short8*)(Pb + (rb + j * 16 + c16) * 64 + ch);
#pragma unroll
      for (int i = 0; i < 4; ++i)
#pragma unroll
        for (int j = 0; j < 4; ++j)
          acc[i][j] = __builtin_amdgcn_mfma_f32_16x16x32_bf16(fa[i], fb[j], acc[i][j], 0, 0, 0);
    }
  }

  if (which == 2) {
#pragma unroll
    for (int i = 0; i < 4; ++i) {
      int m0 = tile_m + wm + i * 16 + quad * 4;
      int bb = m0 >> 11, ss0 = m0 & 2047;
#pragma unroll
      for (int j = 0; j < 4; ++j) {
        int f = (tile_n & 1023) + wn + j * 16 + c16;
        int h = f >> 6, d = f & 63;
        *(ushort4*)(vtb + ((size_t)(bb * 16 + h) * 64 + d) * 2048 + ss0) = pk4(acc[i][j]);
      }
    }
  } else {
    u16* dstb = which ? kb : qb;
#pragma unroll
    for (int i = 0; i < 4; ++i) {
      int full = (tile_n & 1023) + wn + i * 16 + quad * 4;
      int h = full >> 6, d0 = full & 63;
#pragma unroll
      for (int j = 0; j < 4; ++j) {
        int t = tile_m + wm + j * 16 + c16;
        int bb = t >> 11, ss = t & 2047;
        f32x4 v = acc[i][j];
        if (which == 0) { v[0] *= KSCALE; v[1] *= KSCALE; v[2] *= KSCALE; v[3] *= KSCALE; }
        *(ushort4*)(dstb + ((size_t)(bb * 16 + h) * 2048 + ss) * 64 + d0) = pk4(v);
      }
    }
  }
}

// ---------------- k3: flash attention, 8 waves = 4 q-groups x 2 key-halves ----------------
__global__ __launch_bounds__(512) void attn_k(const u16* __restrict__ qb, const u16* __restrict__ kb,
                                              const u16* __restrict__ vtb, const int* __restrict__ mask,
                                              u16* __restrict__ ob) {
  // smem carve: Ks[2][4096]u16 @0, Vs[2][4096]u16 @16384, Ps[128][64]u16 @32768,
  //             mask2[1024]u32 @49152. Epilogue reuses [0,34304) as f32 reduce buf.
  __shared__ __align__(16) char smem[53248];
  u16* const KsB   = (u16*)smem;
  u16* const VsB   = (u16*)(smem + 16384);
  u16* const Ps    = (u16*)(smem + 32768);
  u32* const mask2 = (u32*)(smem + 49152);

  const int tid  = threadIdx.x;
  const int wave = tid >> 6, lane = tid & 63;
  const int c16  = lane & 15, g4 = lane >> 4;
  const int qg   = wave >> 1;        // q 32-block within tile (0..3)
  const int kh   = wave & 1;         // key half of the 64-key tile

  // XCD-bijective remap: flat = x + 16*y; xcd gets a contiguous 64-block chunk
  // = 4 bh x 16 q-blocks, so each bh's 512KB K/V is read within one L2.
  const int f    = blockIdx.x + 16 * blockIdx.y;
  const int i64  = f >> 3;
  const int bh   = (f & 7) * 4 + (i64 >> 4);
  const int q0   = (i64 & 15) * 128;
  const int bidx = bh >> 4, h = bh & 15;

  { // packed keep-masks for all 2048 keys (4 keys/thread)
    int4 m0 = *(const int4*)(mask + bidx * 2048 + tid * 4);
    uint2 dd;
    dd.x = (m0.x ? 0u : 0xFFFFu) | (m0.y ? 0u : 0xFFFF0000u);
    dd.y = (m0.z ? 0u : 0xFFFFu) | (m0.w ? 0u : 0xFFFF0000u);
    *(uint2*)(mask2 + tid * 2) = dd;
  }

  // Q fragments straight from global into registers (both kh waves of a qg
  // load the same rows -- duplicated, cheap)
  const u16* qg_ = qb + ((size_t)bh * 2048 + q0 + qg * 32) * 64;
  short8 qf[2][2];
#pragma unroll
  for (int kc = 0; kc < 2; ++kc)
#pragma unroll
    for (int nj = 0; nj < 2; ++nj)
      qf[kc][nj] = *(const short8*)(qg_ + (nj * 16 + c16) * 64 + kc * 32 + g4 * 8);

  const u16* kg = kb  + (size_t)bh * 2048 * 64;
  const u16* vg = vtb + (size_t)bh * 64 * 2048;
  { // stage K/V tile 0 into buffer 0: 512 threads, one 16B chunk each
    int r  = tid >> 3;
    int cp = (tid & 7) ^ (r & 7);
    gload16(kg + (size_t)r * 64 + cp * 8,   KsB + tid * 8);
    gload16(vg + (size_t)r * 2048 + cp * 8, VsB + tid * 8);
  }
  __syncthreads();

  short8 ones;
#pragma unroll
  for (int i = 0; i < 8; ++i) ones[i] = (short)0x3F80;   // bf16 1.0

  f32x4 O[2][4] = {};   // partial over this wave's key half
  f32x4 L[2] = {};

#pragma unroll 2
  for (int kt = 0; kt < 32; ++kt) {
    if (kt) __syncthreads();   // drains tile-kt loads + frees other buffer
    if (kt + 1 < 32) {
      const int nb = (kt + 1) & 1;
      int r  = tid >> 3;
      int cp = (tid & 7) ^ (r & 7);
      gload16(kg + (size_t)((kt + 1) * 64 + r) * 64 + cp * 8, KsB + nb * 4096 + tid * 8);
      gload16(vg + (size_t)r * 2048 + (kt + 1) * 64 + cp * 8, VsB + nb * 4096 + tid * 8);
    }
    const u16* ksb = KsB + (kt & 1) * 4096;
    const u16* vsb = VsB + (kt & 1) * 4096;

    // S^T[key 32 (this wave's half)][q 32]
    f32x4 S[2][2] = {};
    __builtin_amdgcn_s_setprio(1);
#pragma unroll
    for (int kc = 0; kc < 2; ++kc) {
      const int ch = ((kc * 4 + g4) ^ (c16 & 7)) * 8;
      short8 a[2];
#pragma unroll
      for (int mi = 0; mi < 2; ++mi)
        a[mi] = *(const short8*)(ksb + (kh * 32 + mi * 16 + c16) * 64 + ch);
#pragma unroll
      for (int mi = 0; mi < 2; ++mi)
#pragma unroll
        for (int nj = 0; nj < 2; ++nj)
          S[mi][nj] = __builtin_amdgcn_mfma_f32_16x16x32_bf16(a[mi], qf[kc][nj], S[mi][nj], 0, 0, 0);
    }
    __builtin_amdgcn_s_setprio(0);

    // keep-masks: reg r key = kh*32 + mi*16 + g4*4 + r
    uint2 mk[2];
#pragma unroll
    for (int mi = 0; mi < 2; ++mi)
      mk[mi] = *(const uint2*)(mask2 + kt * 32 + kh * 16 + mi * 8 + g4 * 2);

    // fixed-max softmax: P = exp2(S) & keep, packed to bf16, P -> LDS
    // (column half kh of Ps is wave-private: no barrier)
#pragma unroll
    for (int nj = 0; nj < 2; ++nj) {
      const int q = qg * 32 + nj * 16 + c16;
#pragma unroll
      for (int mi = 0; mi < 2; ++mi) {
        float p0 = __builtin_amdgcn_exp2f(S[mi][nj][0]);
        float p1 = __builtin_amdgcn_exp2f(S[mi][nj][1]);
        float p2 = __builtin_amdgcn_exp2f(S[mi][nj][2]);
        float p3 = __builtin_amdgcn_exp2f(S[mi][nj][3]);
        u32 lo = pkbf2(p0, p1) & mk[mi].x;
        u32 hi = pkbf2(p2, p3) & mk[mi].y;
        uint2 pkd; pkd.x = lo; pkd.y = hi;
        const int c = kh * 4 + mi * 2 + (g4 >> 1);
        *(uint2*)(Ps + q * 64 + ((c ^ (c16 & 7)) * 8 + (g4 & 1) * 4)) = pkd;
      }
    }

    // O[q 32][d 64] += P*V over this wave's 32 keys; L[q] += P*1
    {
      const int ch = ((kh * 4 + g4) ^ (c16 & 7)) * 8;
      short8 a2[2], b2[4];
#pragma unroll
      for (int mi = 0; mi < 2; ++mi)
        a2[mi] = *(const short8*)(Ps + (qg * 32 + mi * 16 + c16) * 64 + ch);
#pragma unroll
      for (int nd = 0; nd < 4; ++nd)
        b2[nd] = *(const short8*)(vsb + (nd * 16 + c16) * 64 + ch);
      __builtin_amdgcn_s_setprio(1);
#pragma unroll
      for (int mi = 0; mi < 2; ++mi) {
#pragma unroll
        for (int nd = 0; nd < 4; ++nd)
          O[mi][nd] = __builtin_amdgcn_mfma_f32_16x16x32_bf16(a2[mi], b2[nd], O[mi][nd], 0, 0, 0);
        L[mi] = __builtin_amdgcn_mfma_f32_16x16x32_bf16(a2[mi], ones, L[mi], 0, 0, 0);
      }
      __builtin_amdgcn_s_setprio(0);
    }
  }

  // epilogue: merge the two key-half partials (fixed-max => pure addition),
  // then O/L. Reduce buffer overlays the dead K/V/P LDS.
  __syncthreads();
  float* const redO = (float*)smem;            // [128][66] (+2 pad: 4-row bank spread)
  float* const redL = (float*)(smem + 33792);  // [128]
  if (kh) {
#pragma unroll
    for (int mi = 0; mi < 2; ++mi)
#pragma unroll
      for (int r = 0; r < 4; ++r) {
        int row = qg * 32 + mi * 16 + g4 * 4 + r;
#pragma unroll
        for (int nd = 0; nd < 4; ++nd)
          redO[row * 66 + nd * 16 + c16] = O[mi][nd][r];
        if (c16 == 0) redL[row] = L[mi][r];
      }
  }
  __syncthreads();
  if (!kh) {
    u16* og = ob + ((size_t)(bidx * 2048 + q0 + qg * 32)) * 1024 + h * 64;
#pragma unroll
    for (int mi = 0; mi < 2; ++mi)
#pragma unroll
      for (int r = 0; r < 4; ++r) {
        int row  = qg * 32 + mi * 16 + g4 * 4 + r;
        int qrow = mi * 16 + g4 * 4 + r;
        float linv = 1.f / (L[mi][r] + redL[row]);
#pragma unroll
        for (int nd = 0; nd < 4; ++nd) {
          float o = O[mi][nd][r] + redO[row * 66 + nd * 16 + c16];
          og[(size_t)qrow * 1024 + nd * 16 + c16] = f2bf(o * linv);
        }
      }
  }
}

// ---------------- k4: output projection, 128x64 tiles (2 blocks/CU) ----------------
__global__ __launch_bounds__(256) void gemm_out(const u16* __restrict__ A, const u16* __restrict__ Bt,
                         float* __restrict__ out) {
  __shared__ __align__(16) u16 As[128 * 64];
  __shared__ __align__(16) u16 Bs[64 * 64];
  const int tid  = threadIdx.x;
  const int wave = tid >> 6, lane = tid & 63;
  const int c16  = lane & 15, quad = lane >> 4;
  const int tile_m = blockIdx.x * 128;
  const int tile_n = blockIdx.y * 64;
  const int wm = wave * 32;
  const int sc   = lane & 7;

  f32x4 acc[4][2] = {};   // [feature blocks][token blocks]

  for (int k0 = 0; k0 < 1024; k0 += 64) {
    __syncthreads();
#pragma unroll
    for (int j = 0; j < 4; ++j) {      // A tile 128x64: 4 loads/thread
      int row = (tid >> 3) + j * 32;
      int cp  = sc ^ (row & 7);
      gload16(A + (size_t)(tile_m + row) * 1024 + k0 + cp * 8, As + row * 64 + sc * 8);
    }
#pragma unroll
    for (int j = 0; j < 2; ++j) {      // B tile 64x64: 2 loads/thread
      int row = (tid >> 3) + j * 32;
      int cp  = sc ^ (row & 7);
      gload16(Bt + (size_t)(tile_n + row) * 1024 + k0 + cp * 8, Bs + row * 64 + sc * 8);
    }
    __syncthreads();
#pragma unroll
    for (int kc = 0; kc < 2; ++kc) {
      const int ch = ((kc * 4 + quad) ^ (c16 & 7)) * 8;
      short8 fa[4], fb[2];
#pragma unroll
      for (int i = 0; i < 4; ++i)
        fa[i] = *(const short8*)(Bs + (i * 16 + c16) * 64 + ch);        // features
#pragma unroll
      for (int j = 0; j < 2; ++j)
        fb[j] = *(const short8*)(As + (wm + j * 16 + c16) * 64 + ch);   // tokens
#pragma unroll
      for (int i = 0; i < 4; ++i)
#pragma unroll
        for (int j = 0; j < 2; ++j)
          acc[i][j] = __builtin_amdgcn_mfma_f32_16x16x32_bf16(fa[i], fb[j], acc[i][j], 0, 0, 0);
    }
  }
#pragma unroll
  for (int i = 0; i < 4; ++i) {
    int f0 = tile_n + i * 16 + quad * 4;
#pragma unroll
    for (int j = 0; j < 2; ++j) {
      int t = tile_m + wm + j * 16 + c16;
      *(f32x4*)(out + (size_t)t * 1024 + f0) = acc[i][j];
    }
  }
}

extern "C" void kernel_launch(void* const* d_in, const int* in_sizes, int n_in,
                              void* d_out, int out_size, void* d_ws, size_t ws_size,
                              hipStream_t stream) {
  (void)in_sizes; (void)n_in; (void)out_size; (void)ws_size;
  const float* x    = (const float*)d_in[0];
  const int*   mask = (const int*)d_in[1];
  const float* wq   = (const float*)d_in[2];
  const float* wk   = (const float*)d_in[3];
  const float* wv   = (const float*)d_in[4];
  const float* wo   = (const float*)d_in[5];
  float* out = (float*)d_out;
  char*  ws  = (char*)d_ws;

  u16* xb   = (u16*)(ws + WS_XB);
  u16* wqkv = (u16*)(ws + WS_WQKV);
  u16* wob  = (u16*)(ws + WS_WOB);
  u16* qbuf = (u16*)(ws + WS_QB);
  u16* kbuf = (u16*)(ws + WS_KB);
  u16* vtb  = (u16*)(ws + WS_VTB);
  u16* obuf = (u16*)(ws + WS_OB);

  convert_k<<<8192, 256, 0, stream>>>(x, wq, wk, wv, wo, xb, wqkv, wob);
  gemm_qkv<<<dim3(32, 24), 256, 0, stream>>>(xb, wqkv, qbuf, kbuf, vtb);
  attn_k<<<dim3(16, 32), 512, 0, stream>>>(qbuf, kbuf, vtb, mask, obuf);
  gemm_out<<<dim3(32, 16), 256, 0, stream>>>(obuf, wob, out);
}